// Round 1
// baseline (439.770 us; speedup 1.0000x reference)
//
#include <hip/hip_runtime.h>
#include <math.h>

#define N 8192
#define D 256
#define BK 32
#define LDSS 132   // LDS row stride in floats: multiple of 4 (float4 align), 132%32=4 -> <=2-way bank aliasing

constexpr float MARGIN = 0.5f;
constexpr float EPS_F  = 1e-10f;

// ---------------------------------------------------------------------------
// Label prep: harness doc says integer inputs arrive as int32, but reference
// dtype is int64. Detect int64 (little-endian: every odd int32 word of the
// first half is 0 -- labels are 0..63) and convert to a clean int32 array.
// ---------------------------------------------------------------------------
__global__ void label_prep_kernel(const int* __restrict__ ys_raw, int* __restrict__ lbl) {
    __shared__ int bad_s;
    const int tid = threadIdx.x;
    if (tid == 0) bad_s = 0;
    __syncthreads();
    int bad = 0;
    // Only touch the first 8192 int32 words (valid for both layouts).
    for (int i = tid; i < N / 2; i += 256) bad |= (ys_raw[2 * i + 1] != 0);
    if (bad) atomicOr(&bad_s, 1);
    __syncthreads();
    const bool is64 = (bad_s == 0);
    for (int i = tid; i < N; i += 256) lbl[i] = is64 ? ys_raw[2 * i] : ys_raw[i];
}

// ---------------------------------------------------------------------------
// Row squared norms: one wave per row, float4 loads, shfl reduce.
// ---------------------------------------------------------------------------
__global__ void sq_kernel(const float* __restrict__ xs, float* __restrict__ sq) {
    const int lane = threadIdx.x & 63;
    const int wave = threadIdx.x >> 6;
    const int row  = blockIdx.x * 4 + wave;
    const float4* x4 = (const float4*)(xs + (size_t)row * D);
    float4 v = x4[lane];
    float s = v.x * v.x + v.y * v.y + v.z * v.z + v.w * v.w;
#pragma unroll
    for (int off = 32; off > 0; off >>= 1) s += __shfl_down(s, off);
    if (lane == 0) sq[row] = s;
}

// ---------------------------------------------------------------------------
// Main fused kernel: 128x128 C-tile per block, 8x8 per thread (split 4+4),
// k-major LDS tiles. Epilogue: dist = sqrt(max(sq_i+sq_j-2dot, EPS)),
// per-row {same,all} sums reduced across tn via shfl_xor, then atomicAdd.
// ---------------------------------------------------------------------------
__global__ __launch_bounds__(256, 4) void pair_kernel(
    const float* __restrict__ xs, const int* __restrict__ lbl,
    const float* __restrict__ sq,
    float* __restrict__ sum_same, float* __restrict__ sum_all) {

    __shared__ float As[BK][LDSS];
    __shared__ float Bs[BK][LDSS];

    const int tid = threadIdx.x;
    const int tm = tid >> 4;        // 0..15 (row group)
    const int tn = tid & 15;        // 0..15 (col group)
    const int i0 = blockIdx.x * 128;
    const int j0 = blockIdx.y * 128;

    float acc[8][8];
#pragma unroll
    for (int a = 0; a < 8; ++a)
#pragma unroll
        for (int b = 0; b < 8; ++b) acc[a][b] = 0.f;

    for (int k0 = 0; k0 < D; k0 += BK) {
        // stage: each tile is 128 rows x BK cols = 1024 float4; 4 per thread
#pragma unroll
        for (int it = 0; it < 4; ++it) {
            const int f4  = it * 256 + tid;
            const int row = f4 >> 3;   // BK/4 = 8 float4 per row
            const int c   = f4 & 7;
            float4 a = *(const float4*)(xs + (size_t)(i0 + row) * D + k0 + c * 4);
            As[c * 4 + 0][row] = a.x;
            As[c * 4 + 1][row] = a.y;
            As[c * 4 + 2][row] = a.z;
            As[c * 4 + 3][row] = a.w;
            float4 b = *(const float4*)(xs + (size_t)(j0 + row) * D + k0 + c * 4);
            Bs[c * 4 + 0][row] = b.x;
            Bs[c * 4 + 1][row] = b.y;
            Bs[c * 4 + 2][row] = b.z;
            Bs[c * 4 + 3][row] = b.w;
        }
        __syncthreads();

#pragma unroll 8
        for (int k = 0; k < BK; ++k) {
            float4 a0 = *(const float4*)&As[k][tm * 4];
            float4 a1 = *(const float4*)&As[k][64 + tm * 4];
            float4 b0 = *(const float4*)&Bs[k][tn * 4];
            float4 b1 = *(const float4*)&Bs[k][64 + tn * 4];
            const float av[8] = {a0.x, a0.y, a0.z, a0.w, a1.x, a1.y, a1.z, a1.w};
            const float bv[8] = {b0.x, b0.y, b0.z, b0.w, b1.x, b1.y, b1.z, b1.w};
#pragma unroll
            for (int ii = 0; ii < 8; ++ii)
#pragma unroll
                for (int jj = 0; jj < 8; ++jj)
                    acc[ii][jj] = fmaf(av[ii], bv[jj], acc[ii][jj]);
        }
        __syncthreads();
    }

    // ---- epilogue ----
    int irow[8], jcol[8];
#pragma unroll
    for (int h = 0; h < 2; ++h)
#pragma unroll
        for (int x = 0; x < 4; ++x) {
            irow[h * 4 + x] = i0 + h * 64 + tm * 4 + x;
            jcol[h * 4 + x] = j0 + h * 64 + tn * 4 + x;
        }
    float sqi[8], sqj[8];
    int yi[8], yj[8];
#pragma unroll
    for (int e = 0; e < 8; ++e) {
        sqi[e] = sq[irow[e]];
        sqj[e] = sq[jcol[e]];
        yi[e]  = lbl[irow[e]];
        yj[e]  = lbl[jcol[e]];
    }

    float rs_same[8], rs_all[8];
#pragma unroll
    for (int ii = 0; ii < 8; ++ii) {
        float ss = 0.f, sa = 0.f;
#pragma unroll
        for (int jj = 0; jj < 8; ++jj) {
            float d2   = sqi[ii] + sqj[jj] - 2.f * acc[ii][jj];
            float dist = sqrtf(fmaxf(d2, EPS_F));
            if (irow[ii] == jcol[jj]) dist = 1e-5f;  // exact diagonal: sqrt(EPS)
            sa += dist;
            if (yi[ii] == yj[jj]) ss += dist;
        }
        rs_same[ii] = ss;
        rs_all[ii]  = sa;
    }

    // reduce across tn (threads sharing the same 8 rows): tn = low 4 lane bits
#pragma unroll
    for (int off = 1; off < 16; off <<= 1) {
#pragma unroll
        for (int ii = 0; ii < 8; ++ii) {
            rs_same[ii] += __shfl_xor(rs_same[ii], off);
            rs_all[ii]  += __shfl_xor(rs_all[ii], off);
        }
    }
    if (tn == 0) {
#pragma unroll
        for (int ii = 0; ii < 8; ++ii) {
            atomicAdd(&sum_same[irow[ii]], rs_same[ii]);
            atomicAdd(&sum_all[irow[ii]],  rs_all[ii]);
        }
    }
}

// ---------------------------------------------------------------------------
// Finalize: label histogram -> per-row loss term -> mean.
// ---------------------------------------------------------------------------
__global__ void finalize_kernel(const float* __restrict__ sum_same,
                                const float* __restrict__ sum_all,
                                const int* __restrict__ lbl,
                                float* __restrict__ out) {
    __shared__ int hist[64];
    __shared__ float wsums[4];
    const int tid = threadIdx.x;
    if (tid < 64) hist[tid] = 0;
    __syncthreads();
    for (int i = tid; i < N; i += 256) atomicAdd(&hist[lbl[i]], 1);
    __syncthreads();

    float local = 0.f;
    for (int i = tid; i < N; i += 256) {
        const float cnt = (float)hist[lbl[i]];
        const float ss  = sum_same[i];
        const float sa  = sum_all[i];
        const float ap  = ss / cnt;
        const float an  = (sa - ss) / ((float)N - cnt);
        local += fmaxf(ap - an + MARGIN, 0.f);
    }
#pragma unroll
    for (int off = 32; off > 0; off >>= 1) local += __shfl_down(local, off);
    const int lane = tid & 63, wave = tid >> 6;
    if (lane == 0) wsums[wave] = local;
    __syncthreads();
    if (tid == 0) out[0] = (wsums[0] + wsums[1] + wsums[2] + wsums[3]) / (float)N;
}

// ---------------------------------------------------------------------------
extern "C" void kernel_launch(void* const* d_in, const int* in_sizes, int n_in,
                              void* d_out, int out_size, void* d_ws, size_t ws_size,
                              hipStream_t stream) {
    const float* xs     = (const float*)d_in[0];
    const int*   ys_raw = (const int*)d_in[1];

    float* ws       = (float*)d_ws;
    float* sum_same = ws;                 // [N]
    float* sum_all  = ws + N;             // [N]
    float* sqv      = ws + 2 * N;         // [N]
    int*   lbl      = (int*)(ws + 3 * N); // [N]

    hipMemsetAsync(d_ws, 0, (size_t)2 * N * sizeof(float), stream);

    label_prep_kernel<<<1, 256, 0, stream>>>(ys_raw, lbl);
    sq_kernel<<<N / 4, 256, 0, stream>>>(xs, sqv);

    dim3 grid(N / 128, N / 128);
    pair_kernel<<<grid, 256, 0, stream>>>(xs, lbl, sqv, sum_same, sum_all);

    finalize_kernel<<<1, 256, 0, stream>>>(sum_same, sum_all, lbl, (float*)d_out);
}

// Round 2
// 139.364 us; speedup vs baseline: 3.1556x; 3.1556x over previous
//
#include <hip/hip_runtime.h>
#include <math.h>

#define N 8192
#define D 256
#define BK 32

typedef _Float16 half8 __attribute__((ext_vector_type(8)));
typedef float f32x4 __attribute__((ext_vector_type(4)));

constexpr float MARGIN = 0.5f;
constexpr float EPS_F  = 1e-10f;

// ---------------------------------------------------------------------------
// async global->LDS, 16B per lane. LDS dest = wave-uniform base + lane*16.
// ---------------------------------------------------------------------------
__device__ inline void load_lds16(const void* g, void* l) {
    __builtin_amdgcn_global_load_lds(
        (const __attribute__((address_space(1))) void*)g,
        (__attribute__((address_space(3))) void*)l, 16, 0, 0);
}

// ---------------------------------------------------------------------------
// Label prep: detect int64 vs int32 layout, normalize to int32.
// ---------------------------------------------------------------------------
__global__ void label_prep_kernel(const int* __restrict__ ys_raw, int* __restrict__ lbl) {
    __shared__ int bad_s;
    const int tid = threadIdx.x;
    if (tid == 0) bad_s = 0;
    __syncthreads();
    int bad = 0;
    for (int i = tid; i < N / 2; i += 256) bad |= (ys_raw[2 * i + 1] != 0);
    if (bad) atomicOr(&bad_s, 1);
    __syncthreads();
    const bool is64 = (bad_s == 0);
    for (int i = tid; i < N; i += 256) lbl[i] = is64 ? ys_raw[2 * i] : ys_raw[i];
}

// ---------------------------------------------------------------------------
// Row squared norms in fp32 (exact, matches reference precision path).
// ---------------------------------------------------------------------------
__global__ void sq_kernel(const float* __restrict__ xs, float* __restrict__ sq) {
    const int lane = threadIdx.x & 63;
    const int wave = threadIdx.x >> 6;
    const int row  = blockIdx.x * 4 + wave;
    const float4* x4 = (const float4*)(xs + (size_t)row * D);
    float4 v = x4[lane];
    float s = v.x * v.x + v.y * v.y + v.z * v.z + v.w * v.w;
#pragma unroll
    for (int off = 32; off > 0; off >>= 1) s += __shfl_down(s, off);
    if (lane == 0) sq[row] = s;
}

// ---------------------------------------------------------------------------
// fp32 -> fp16 conversion, 8 elements/thread, vectorized.
// ---------------------------------------------------------------------------
__global__ void cvt_kernel(const float* __restrict__ xs, _Float16* __restrict__ x16) {
    const int i = blockIdx.x * 256 + threadIdx.x;   // handles 8 floats
    const float4* s = (const float4*)xs;
    float4 a = s[2 * i], b = s[2 * i + 1];
    half8 h = { (_Float16)a.x, (_Float16)a.y, (_Float16)a.z, (_Float16)a.w,
                (_Float16)b.x, (_Float16)b.y, (_Float16)b.z, (_Float16)b.w };
    *(half8*)(x16 + (size_t)i * 8) = h;
}

// ---------------------------------------------------------------------------
// MFMA pair kernel: 128x128 C-tile per block, 4 waves (2x2 of 64x64 each),
// mfma_f32_16x16x32_f16, K=256 in 8 steps of BK=32, global_load_lds staging.
// Epilogue: dist = sqrt(max(sq_i+sq_j-2dot,EPS)), per-row {same,all} sums.
// ---------------------------------------------------------------------------
__global__ __launch_bounds__(256) void pair_kernel(
    const _Float16* __restrict__ x16, const int* __restrict__ lbl,
    const float* __restrict__ sq,
    float* __restrict__ sum_same, float* __restrict__ sum_all) {

    __shared__ _Float16 As[128 * BK];
    __shared__ _Float16 Bs[128 * BK];

    const int tid  = threadIdx.x;
    const int w    = tid >> 6;        // wave 0..3
    const int lane = tid & 63;
    const int wm   = w >> 1;          // 0..1 (row half)
    const int wn   = w & 1;           // 0..1 (col half)
    const int cl   = lane & 15;       // fragment col / row-within-16
    const int g    = lane >> 4;       // k-group 0..3

    const int i0 = blockIdx.x * 128;
    const int j0 = blockIdx.y * 128;

    f32x4 acc[4][4];
#pragma unroll
    for (int a = 0; a < 4; ++a)
#pragma unroll
        for (int b = 0; b < 4; ++b) acc[a][b] = (f32x4){0.f, 0.f, 0.f, 0.f};

    for (int k0 = 0; k0 < D; k0 += BK) {
        // --- stage A and B tiles: 512 16B-chunks each; chunk c -> row=c>>2, kc=c&3
#pragma unroll
        for (int r = 0; r < 2; ++r) {
            const int c   = r * 256 + w * 64 + lane;
            const int row = c >> 2;
            const int kc  = c & 3;
            const _Float16* ga = x16 + (size_t)(i0 + row) * D + k0 + kc * 8;
            const _Float16* gb = x16 + (size_t)(j0 + row) * D + k0 + kc * 8;
            _Float16* la = &As[(size_t)(r * 256 + w * 64) * 8];  // wave-uniform base
            _Float16* lb = &Bs[(size_t)(r * 256 + w * 64) * 8];
            load_lds16(ga, la);
            load_lds16(gb, lb);
        }
        __syncthreads();   // compiler emits vmcnt(0) drain before s_barrier

        half8 af[4], bf[4];
#pragma unroll
        for (int mf = 0; mf < 4; ++mf)
            af[mf] = *(const half8*)&As[(wm * 64 + mf * 16 + cl) * BK + g * 8];
#pragma unroll
        for (int nf = 0; nf < 4; ++nf)
            bf[nf] = *(const half8*)&Bs[(wn * 64 + nf * 16 + cl) * BK + g * 8];

#pragma unroll
        for (int mf = 0; mf < 4; ++mf)
#pragma unroll
            for (int nf = 0; nf < 4; ++nf)
                acc[mf][nf] = __builtin_amdgcn_mfma_f32_16x16x32_f16(
                    af[mf], bf[nf], acc[mf][nf], 0, 0, 0);

        __syncthreads();
    }

    // ---- epilogue ----
    // C layout (m89): col = lane&15, row = (lane>>4)*4 + reg
    const int rowbase = i0 + wm * 64;
    const int colbase = j0 + wn * 64;

    float sqj_[4];
    int   yj_[4];
#pragma unroll
    for (int nf = 0; nf < 4; ++nf) {
        const int c = colbase + nf * 16 + cl;
        sqj_[nf] = sq[c];
        yj_[nf]  = lbl[c];
    }

    float rs_same[16], rs_all[16];
#pragma unroll
    for (int mf = 0; mf < 4; ++mf) {
#pragma unroll
        for (int r = 0; r < 4; ++r) {
            const int row = rowbase + mf * 16 + g * 4 + r;
            const float sqi = sq[row];
            const int   yi  = lbl[row];
            float ss = 0.f, sa = 0.f;
#pragma unroll
            for (int nf = 0; nf < 4; ++nf) {
                const int col = colbase + nf * 16 + cl;
                float d2   = sqi + sqj_[nf] - 2.f * acc[mf][nf][r];
                float dist = sqrtf(fmaxf(d2, EPS_F));
                if (row == col) dist = 1e-5f;   // exact diagonal: sqrt(EPS)
                sa += dist;
                if (yi == yj_[nf]) ss += dist;
            }
            rs_same[mf * 4 + r] = ss;
            rs_all[mf * 4 + r]  = sa;
        }
    }

    // reduce across the 16-lane col group (xor masks 1,2,4,8 stay within group)
#pragma unroll
    for (int off = 1; off < 16; off <<= 1) {
#pragma unroll
        for (int e = 0; e < 16; ++e) {
            rs_same[e] += __shfl_xor(rs_same[e], off);
            rs_all[e]  += __shfl_xor(rs_all[e], off);
        }
    }
    if (cl == 0) {
#pragma unroll
        for (int mf = 0; mf < 4; ++mf)
#pragma unroll
            for (int r = 0; r < 4; ++r) {
                const int row = rowbase + mf * 16 + g * 4 + r;
                atomicAdd(&sum_same[row], rs_same[mf * 4 + r]);
                atomicAdd(&sum_all[row],  rs_all[mf * 4 + r]);
            }
    }
}

// ---------------------------------------------------------------------------
// Finalize: label histogram -> per-row loss term -> mean.
// ---------------------------------------------------------------------------
__global__ void finalize_kernel(const float* __restrict__ sum_same,
                                const float* __restrict__ sum_all,
                                const int* __restrict__ lbl,
                                float* __restrict__ out) {
    __shared__ int hist[64];
    __shared__ float wsums[4];
    const int tid = threadIdx.x;
    if (tid < 64) hist[tid] = 0;
    __syncthreads();
    for (int i = tid; i < N; i += 256) atomicAdd(&hist[lbl[i]], 1);
    __syncthreads();

    float local = 0.f;
    for (int i = tid; i < N; i += 256) {
        const float cnt = (float)hist[lbl[i]];
        const float ss  = sum_same[i];
        const float sa  = sum_all[i];
        const float ap  = ss / cnt;
        const float an  = (sa - ss) / ((float)N - cnt);
        local += fmaxf(ap - an + MARGIN, 0.f);
    }
#pragma unroll
    for (int off = 32; off > 0; off >>= 1) local += __shfl_down(local, off);
    const int lane = tid & 63, wave = tid >> 6;
    if (lane == 0) wsums[wave] = local;
    __syncthreads();
    if (tid == 0) out[0] = (wsums[0] + wsums[1] + wsums[2] + wsums[3]) / (float)N;
}

// ---------------------------------------------------------------------------
extern "C" void kernel_launch(void* const* d_in, const int* in_sizes, int n_in,
                              void* d_out, int out_size, void* d_ws, size_t ws_size,
                              hipStream_t stream) {
    const float* xs     = (const float*)d_in[0];
    const int*   ys_raw = (const int*)d_in[1];

    float* ws        = (float*)d_ws;
    float* sum_same  = ws;                       // [N]
    float* sum_all   = ws + N;                   // [N]
    float* sqv       = ws + 2 * N;               // [N]
    int*   lbl       = (int*)(ws + 3 * N);       // [N]
    _Float16* x16    = (_Float16*)(ws + 4 * N);  // [N*D] fp16 (4 MB)

    hipMemsetAsync(d_ws, 0, (size_t)2 * N * sizeof(float), stream);

    label_prep_kernel<<<1, 256, 0, stream>>>(ys_raw, lbl);
    sq_kernel<<<N / 4, 256, 0, stream>>>(xs, sqv);
    cvt_kernel<<<(N * D / 8) / 256, 256, 0, stream>>>(xs, x16);

    dim3 grid(N / 128, N / 128);
    pair_kernel<<<grid, 256, 0, stream>>>(x16, lbl, sqv, sum_same, sum_all);

    finalize_kernel<<<1, 256, 0, stream>>>(sum_same, sum_all, lbl, (float*)d_out);
}

// Round 3
// 111.496 us; speedup vs baseline: 3.9442x; 1.2499x over previous
//
#include <hip/hip_runtime.h>
#include <math.h>

#define N 8192
#define D 256
#define BK 32
#define TILE 128
#define NB (N / TILE)              // 64 panels
#define NBLK (NB * (NB + 1) / 2)   // 2080 upper-triangular blocks

typedef _Float16 half8 __attribute__((ext_vector_type(8)));
typedef _Float16 half4 __attribute__((ext_vector_type(4)));
typedef float f32x4 __attribute__((ext_vector_type(4)));

constexpr float MARGIN = 0.5f;
constexpr float EPS_F  = 1e-10f;

// ---------------------------------------------------------------------------
// async global->LDS, 16B per lane. LDS dest = wave-uniform base + lane*16.
// ---------------------------------------------------------------------------
__device__ inline void load_lds16(const void* g, void* l) {
    __builtin_amdgcn_global_load_lds(
        (const __attribute__((address_space(1))) void*)g,
        (__attribute__((address_space(3))) void*)l, 16, 0, 0);
}

// ---------------------------------------------------------------------------
// Label prep: detect int64 vs int32 layout, normalize to int32.
// ---------------------------------------------------------------------------
__global__ void label_prep_kernel(const int* __restrict__ ys_raw, int* __restrict__ lbl) {
    __shared__ int bad_s;
    const int tid = threadIdx.x;
    if (tid == 0) bad_s = 0;
    __syncthreads();
    int bad = 0;
    for (int i = tid; i < N / 2; i += 256) bad |= (ys_raw[2 * i + 1] != 0);
    if (bad) atomicOr(&bad_s, 1);
    __syncthreads();
    const bool is64 = (bad_s == 0);
    for (int i = tid; i < N; i += 256) lbl[i] = is64 ? ys_raw[2 * i] : ys_raw[i];
}

// ---------------------------------------------------------------------------
// Fused prep: fp32->fp16 convert + exact fp32 row squared norms (one pass).
// One wave per row: 64 lanes x float4.
// ---------------------------------------------------------------------------
__global__ void prep_kernel(const float* __restrict__ xs,
                            _Float16* __restrict__ x16, float* __restrict__ sq) {
    const int lane = threadIdx.x & 63;
    const int wave = threadIdx.x >> 6;
    const int row  = blockIdx.x * 4 + wave;
    const float4 v = ((const float4*)(xs + (size_t)row * D))[lane];
    half4 h = { (_Float16)v.x, (_Float16)v.y, (_Float16)v.z, (_Float16)v.w };
    *(half4*)(x16 + (size_t)row * D + lane * 4) = h;
    float s = v.x * v.x + v.y * v.y + v.z * v.z + v.w * v.w;
#pragma unroll
    for (int off = 32; off > 0; off >>= 1) s += __shfl_down(s, off);
    if (lane == 0) sq[row] = s;
}

// ---------------------------------------------------------------------------
// Symmetric MFMA pair kernel. Grid = 2080 upper-tri blocks (bi<=bj).
// 128x128 C-tile, 4 waves (2x2 of 64x64), mfma_f32_16x16x32_f16, BK=32,
// double-buffered global_load_lds staging (T3-minimum 2-phase pipeline).
// Off-diag blocks scatter row-sums (panel bi) AND col-sums (panel bj);
// diag blocks use only col-sums (== row-sums by in-block symmetry, cheap dir).
// ---------------------------------------------------------------------------
__global__ __launch_bounds__(256) void pair_kernel(
    const _Float16* __restrict__ x16, const int* __restrict__ lbl,
    const float* __restrict__ sq,
    float* __restrict__ sum_same, float* __restrict__ sum_all) {

    __shared__ _Float16 As[2][TILE * BK];
    __shared__ _Float16 Bs[2][TILE * BK];

    // ---- decode upper-triangular block index: t -> (bi, bj), bi<=bj ----
    const int t = blockIdx.x;
    int bj = (int)((sqrtf(8.f * (float)t + 1.f) - 1.f) * 0.5f);
    while ((bj + 1) * (bj + 2) / 2 <= t) ++bj;
    while (bj * (bj + 1) / 2 > t) --bj;
    const int bi   = t - bj * (bj + 1) / 2;
    const bool diag = (bi == bj);
    const int i0 = bi * TILE;
    const int j0 = bj * TILE;

    const int tid  = threadIdx.x;
    const int w    = tid >> 6;
    const int lane = tid & 63;
    const int wm   = w >> 1;
    const int wn   = w & 1;
    const int cl   = lane & 15;
    const int g    = lane >> 4;

    f32x4 acc[4][4];
#pragma unroll
    for (int a = 0; a < 4; ++a)
#pragma unroll
        for (int b = 0; b < 4; ++b) acc[a][b] = (f32x4){0.f, 0.f, 0.f, 0.f};

    // staging: 512 16B-chunks per tile; chunk c -> row=c>>2, kc=c&3 (linear LDS)
    const int c0  = w * 64 + lane;
    const int r0  = c0 >> 2, kc0 = c0 & 3;
    const int c1  = 256 + c0;
    const int r1  = c1 >> 2, kc1 = c1 & 3;

#define STAGE(buf, k0)                                                          \
    do {                                                                        \
        load_lds16(x16 + (size_t)(i0 + r0) * D + (k0) + kc0 * 8,                \
                   &As[buf][(size_t)(w * 64) * 8]);                             \
        load_lds16(x16 + (size_t)(j0 + r0) * D + (k0) + kc0 * 8,                \
                   &Bs[buf][(size_t)(w * 64) * 8]);                             \
        load_lds16(x16 + (size_t)(i0 + r1) * D + (k0) + kc1 * 8,                \
                   &As[buf][(size_t)(256 + w * 64) * 8]);                       \
        load_lds16(x16 + (size_t)(j0 + r1) * D + (k0) + kc1 * 8,                \
                   &Bs[buf][(size_t)(256 + w * 64) * 8]);                       \
    } while (0)

    STAGE(0, 0);
    __syncthreads();   // drain prologue stage

#pragma unroll
    for (int t8 = 0; t8 < 8; ++t8) {
        const int cur = t8 & 1;
        if (t8 < 7) STAGE(cur ^ 1, (t8 + 1) * BK);   // prefetch next tile

        half8 af[4], bf[4];
#pragma unroll
        for (int mf = 0; mf < 4; ++mf)
            af[mf] = *(const half8*)&As[cur][(wm * 64 + mf * 16 + cl) * BK + g * 8];
#pragma unroll
        for (int nf = 0; nf < 4; ++nf)
            bf[nf] = *(const half8*)&Bs[cur][(wn * 64 + nf * 16 + cl) * BK + g * 8];

#pragma unroll
        for (int mf = 0; mf < 4; ++mf)
#pragma unroll
            for (int nf = 0; nf < 4; ++nf)
                acc[mf][nf] = __builtin_amdgcn_mfma_f32_16x16x32_f16(
                    af[mf], bf[nf], acc[mf][nf], 0, 0, 0);

        __syncthreads();   // drains this iter's prefetch before next reads
    }
#undef STAGE

    // ---- epilogue ----
    // C layout (m89): col = lane&15 (j-local), row = (lane>>4)*4 + reg (i-local)
    const int rowbase = i0 + wm * 64;
    const int colbase = j0 + wn * 64;

    float sqj_[4];
    int   yj_[4];
#pragma unroll
    for (int nf = 0; nf < 4; ++nf) {
        const int c = colbase + nf * 16 + cl;
        sqj_[nf] = sq[c];
        yj_[nf]  = lbl[c];
    }

    float cs_all[4], cs_same[4];      // col sums (over i) -> rows of panel bj
#pragma unroll
    for (int nf = 0; nf < 4; ++nf) { cs_all[nf] = 0.f; cs_same[nf] = 0.f; }
    float rs_all[16], rs_same[16];    // row sums (over j) -> rows of panel bi
#pragma unroll
    for (int e = 0; e < 16; ++e) { rs_all[e] = 0.f; rs_same[e] = 0.f; }

#pragma unroll
    for (int mf = 0; mf < 4; ++mf) {
#pragma unroll
        for (int r = 0; r < 4; ++r) {
            const int row   = rowbase + mf * 16 + g * 4 + r;
            const float sqi = sq[row];
            const int   yi  = lbl[row];
#pragma unroll
            for (int nf = 0; nf < 4; ++nf) {
                float d2   = sqi + sqj_[nf] - 2.f * acc[mf][nf][r];
                float dist = sqrtf(fmaxf(d2, EPS_F));
                if (diag) {
                    const int col = colbase + nf * 16 + cl;
                    if (row == col) dist = 1e-5f;   // exact diagonal sqrt(EPS)
                }
                const float dm = (yi == yj_[nf]) ? dist : 0.f;
                cs_all[nf] += dist;
                cs_same[nf] += dm;
                rs_all[mf * 4 + r] += dist;
                rs_same[mf * 4 + r] += dm;
            }
        }
    }

    // cheap direction: reduce col sums across the 4 g-groups (xor 16, 32)
#pragma unroll
    for (int off = 16; off < 64; off <<= 1) {
#pragma unroll
        for (int nf = 0; nf < 4; ++nf) {
            cs_all[nf]  += __shfl_xor(cs_all[nf], off);
            cs_same[nf] += __shfl_xor(cs_same[nf], off);
        }
    }
    if (g == 0) {
#pragma unroll
        for (int nf = 0; nf < 4; ++nf) {
            const int c = colbase + nf * 16 + cl;
            atomicAdd(&sum_same[c], cs_same[nf]);
            atomicAdd(&sum_all[c],  cs_all[nf]);
        }
    }

    // expensive direction: only for off-diagonal blocks (row sums over j)
    if (!diag) {
#pragma unroll
        for (int off = 1; off < 16; off <<= 1) {
#pragma unroll
            for (int e = 0; e < 16; ++e) {
                rs_all[e]  += __shfl_xor(rs_all[e], off);
                rs_same[e] += __shfl_xor(rs_same[e], off);
            }
        }
        if (cl == 0) {
#pragma unroll
            for (int mf = 0; mf < 4; ++mf)
#pragma unroll
                for (int r = 0; r < 4; ++r) {
                    const int row = rowbase + mf * 16 + g * 4 + r;
                    atomicAdd(&sum_same[row], rs_same[mf * 4 + r]);
                    atomicAdd(&sum_all[row],  rs_all[mf * 4 + r]);
                }
        }
    }
}

// ---------------------------------------------------------------------------
// Finalize: label histogram -> per-row loss term -> mean.
// ---------------------------------------------------------------------------
__global__ void finalize_kernel(const float* __restrict__ sum_same,
                                const float* __restrict__ sum_all,
                                const int* __restrict__ lbl,
                                float* __restrict__ out) {
    __shared__ int hist[64];
    __shared__ float wsums[4];
    const int tid = threadIdx.x;
    if (tid < 64) hist[tid] = 0;
    __syncthreads();
    for (int i = tid; i < N; i += 256) atomicAdd(&hist[lbl[i]], 1);
    __syncthreads();

    float local = 0.f;
    for (int i = tid; i < N; i += 256) {
        const float cnt = (float)hist[lbl[i]];
        const float ss  = sum_same[i];
        const float sa  = sum_all[i];
        const float ap  = ss / cnt;
        const float an  = (sa - ss) / ((float)N - cnt);
        local += fmaxf(ap - an + MARGIN, 0.f);
    }
#pragma unroll
    for (int off = 32; off > 0; off >>= 1) local += __shfl_down(local, off);
    const int lane = tid & 63, wave = tid >> 6;
    if (lane == 0) wsums[wave] = local;
    __syncthreads();
    if (tid == 0) out[0] = (wsums[0] + wsums[1] + wsums[2] + wsums[3]) / (float)N;
}

// ---------------------------------------------------------------------------
extern "C" void kernel_launch(void* const* d_in, const int* in_sizes, int n_in,
                              void* d_out, int out_size, void* d_ws, size_t ws_size,
                              hipStream_t stream) {
    const float* xs     = (const float*)d_in[0];
    const int*   ys_raw = (const int*)d_in[1];

    float* ws        = (float*)d_ws;
    float* sum_same  = ws;                       // [N]
    float* sum_all   = ws + N;                   // [N]
    float* sqv       = ws + 2 * N;               // [N]
    int*   lbl       = (int*)(ws + 3 * N);       // [N]
    _Float16* x16    = (_Float16*)(ws + 4 * N);  // [N*D] fp16 (4 MB)

    hipMemsetAsync(d_ws, 0, (size_t)2 * N * sizeof(float), stream);

    label_prep_kernel<<<1, 256, 0, stream>>>(ys_raw, lbl);
    prep_kernel<<<N / 4, 256, 0, stream>>>(xs, x16, sqv);

    pair_kernel<<<NBLK, 256, 0, stream>>>(x16, lbl, sqv, sum_same, sum_all);

    finalize_kernel<<<1, 256, 0, stream>>>(sum_same, sum_all, lbl, (float*)d_out);
}

// Round 4
// 81.815 us; speedup vs baseline: 5.3752x; 1.3628x over previous
//
#include <hip/hip_runtime.h>
#include <math.h>

#define N 8192
#define D 256
#define BK 32
#define TILE 128
#define NB (N / TILE)              // 64 panels
#define NBLK (NB * (NB + 1) / 2)   // 2080 upper-triangular blocks

typedef _Float16 half8 __attribute__((ext_vector_type(8)));
typedef _Float16 half4 __attribute__((ext_vector_type(4)));
typedef float f32x4 __attribute__((ext_vector_type(4)));

constexpr float MARGIN = 0.5f;
constexpr float EPS_F  = 1e-10f;

// ---------------------------------------------------------------------------
// async global->LDS, 16B per lane. LDS dest = wave-uniform base + lane*16.
// ---------------------------------------------------------------------------
__device__ inline void load_lds16(const void* g, void* l) {
    __builtin_amdgcn_global_load_lds(
        (const __attribute__((address_space(1))) void*)g,
        (__attribute__((address_space(3))) void*)l, 16, 0, 0);
}

// ---------------------------------------------------------------------------
// Label prep: detect int64 vs int32 layout (per-block slice; random 0..63
// labels make a false int64-positive on int32 data ~(1/64)^256), normalize
// to int32, and build the 64-bin global histogram.
// ---------------------------------------------------------------------------
__global__ void label_prep_kernel(const int* __restrict__ ys_raw,
                                  int* __restrict__ lbl, int* __restrict__ hist) {
    __shared__ int lh[64];
    __shared__ int bad_s;
    const int tid  = threadIdx.x;
    const int base = blockIdx.x * 512;
    if (tid < 64) lh[tid] = 0;
    if (tid == 0) bad_s = 0;
    __syncthreads();
    int bad = 0;
    for (int i = tid; i < 512; i += 256) bad |= (ys_raw[2 * (base + i) + 1] != 0);
    if (bad) atomicOr(&bad_s, 1);
    __syncthreads();
    const bool is64 = (bad_s == 0);
    for (int i = tid; i < 512; i += 256) {
        const int v = is64 ? ys_raw[2 * (base + i)] : ys_raw[base + i];
        lbl[base + i] = v;
        atomicAdd(&lh[v & 63], 1);
    }
    __syncthreads();
    if (tid < 64) atomicAdd(&hist[tid], lh[tid]);
}

// ---------------------------------------------------------------------------
// Fused prep: fp32->fp16 convert + exact fp32 row squared norms (one pass).
// ---------------------------------------------------------------------------
__global__ void prep_kernel(const float* __restrict__ xs,
                            _Float16* __restrict__ x16, float* __restrict__ sq) {
    const int lane = threadIdx.x & 63;
    const int wave = threadIdx.x >> 6;
    const int row  = blockIdx.x * 4 + wave;
    const float4 v = ((const float4*)(xs + (size_t)row * D))[lane];
    half4 h = { (_Float16)v.x, (_Float16)v.y, (_Float16)v.z, (_Float16)v.w };
    *(half4*)(x16 + (size_t)row * D + lane * 4) = h;
    float s = v.x * v.x + v.y * v.y + v.z * v.z + v.w * v.w;
#pragma unroll
    for (int off = 32; off > 0; off >>= 1) s += __shfl_down(s, off);
    if (lane == 0) sq[row] = s;
}

// ---------------------------------------------------------------------------
// Symmetric MFMA pair kernel, counted-vmcnt double-buffered schedule.
// Grid = 2080 upper-tri blocks (bi<=bj); 128x128 tile, 4 waves (2x2 of 64x64).
// Row/col sums via value-split butterflies; 4 atomics per lane.
// ---------------------------------------------------------------------------
__global__ __launch_bounds__(256) void pair_kernel(
    const _Float16* __restrict__ x16, const int* __restrict__ lbl,
    const float* __restrict__ sq,
    float* __restrict__ sum_same, float* __restrict__ sum_all) {

    __shared__ _Float16 As[2][TILE * BK];
    __shared__ _Float16 Bs[2][TILE * BK];

    // ---- decode upper-triangular block index: t -> (bi, bj), bi<=bj ----
    const int t = blockIdx.x;
    int bj = (int)((sqrtf(8.f * (float)t + 1.f) - 1.f) * 0.5f);
    while ((bj + 1) * (bj + 2) / 2 <= t) ++bj;
    while (bj * (bj + 1) / 2 > t) --bj;
    const int bi    = t - bj * (bj + 1) / 2;
    const bool diag = (bi == bj);
    const int i0 = bi * TILE;
    const int j0 = bj * TILE;

    const int tid  = threadIdx.x;
    const int w    = tid >> 6;
    const int lane = tid & 63;
    const int wm   = w >> 1;
    const int wn   = w & 1;
    const int cl   = lane & 15;
    const int g    = lane >> 4;

    f32x4 acc[4][4];
#pragma unroll
    for (int a = 0; a < 4; ++a)
#pragma unroll
        for (int b = 0; b < 4; ++b) acc[a][b] = (f32x4){0.f, 0.f, 0.f, 0.f};

    // staging: 512 16B-chunks per tile; chunk c -> row=c>>2, kc=c&3 (linear LDS)
    const int c0 = w * 64 + lane;
    const int r0 = c0 >> 2, kc0 = c0 & 3;
    const int c1 = 256 + c0;
    const int r1 = c1 >> 2, kc1 = c1 & 3;

#define STAGE(buf, k0)                                                          \
    do {                                                                        \
        load_lds16(x16 + (size_t)(i0 + r0) * D + (k0) + kc0 * 8,                \
                   &As[buf][(size_t)(w * 64) * 8]);                             \
        load_lds16(x16 + (size_t)(j0 + r0) * D + (k0) + kc0 * 8,                \
                   &Bs[buf][(size_t)(w * 64) * 8]);                             \
        load_lds16(x16 + (size_t)(i0 + r1) * D + (k0) + kc1 * 8,                \
                   &As[buf][(size_t)(256 + w * 64) * 8]);                       \
        load_lds16(x16 + (size_t)(j0 + r1) * D + (k0) + kc1 * 8,                \
                   &Bs[buf][(size_t)(256 + w * 64) * 8]);                       \
    } while (0)

    STAGE(0, 0);   // prologue: 4 loads in flight

#pragma unroll
    for (int t8 = 0; t8 < 8; ++t8) {
        const int cur = t8 & 1;
        if (t8 < 7) STAGE(cur ^ 1, (t8 + 1) * BK);   // prefetch next (4 more in flight)

        // wait only for buf[cur]'s 4 loads (issued one iter ago); prefetch stays in flight
        if (t8 < 7) asm volatile("s_waitcnt vmcnt(4)" ::: "memory");
        else        asm volatile("s_waitcnt vmcnt(0)" ::: "memory");
        __builtin_amdgcn_s_barrier();   // all waves' chunk-cur loads landed

        half8 af[4], bf[4];
#pragma unroll
        for (int mf = 0; mf < 4; ++mf)
            af[mf] = *(const half8*)&As[cur][(wm * 64 + mf * 16 + cl) * BK + g * 8];
#pragma unroll
        for (int nf = 0; nf < 4; ++nf)
            bf[nf] = *(const half8*)&Bs[cur][(wn * 64 + nf * 16 + cl) * BK + g * 8];

#pragma unroll
        for (int mf = 0; mf < 4; ++mf)
#pragma unroll
            for (int nf = 0; nf < 4; ++nf)
                acc[mf][nf] = __builtin_amdgcn_mfma_f32_16x16x32_f16(
                    af[mf], bf[nf], acc[mf][nf], 0, 0, 0);

        // all waves finished reading buf[cur] -> next iter may overwrite it
        if (t8 < 7) __builtin_amdgcn_s_barrier();
    }
#undef STAGE

    // ---- epilogue ----
    // C layout (m89): col = lane&15 (j-local), row = (lane>>4)*4 + reg (i-local)
    const int rowbase = i0 + wm * 64;
    const int colbase = j0 + wn * 64;

    float sqj_[4];
    int   yj_[4];
#pragma unroll
    for (int nf = 0; nf < 4; ++nf) {
        const int c = colbase + nf * 16 + cl;
        sqj_[nf] = sq[c];
        yj_[nf]  = lbl[c];
    }

    float cs_all[4], cs_same[4];      // col sums (over i) -> rows of panel bj
#pragma unroll
    for (int nf = 0; nf < 4; ++nf) { cs_all[nf] = 0.f; cs_same[nf] = 0.f; }
    float rs_all[16], rs_same[16];    // row sums (over j) -> rows of panel bi
#pragma unroll
    for (int e = 0; e < 16; ++e) { rs_all[e] = 0.f; rs_same[e] = 0.f; }

#pragma unroll
    for (int mf = 0; mf < 4; ++mf) {
#pragma unroll
        for (int r = 0; r < 4; ++r) {
            const int row   = rowbase + mf * 16 + g * 4 + r;
            const float sqi = sq[row];
            const int   yi  = lbl[row];
#pragma unroll
            for (int nf = 0; nf < 4; ++nf) {
                float d2   = sqi + sqj_[nf] - 2.f * acc[mf][nf][r];
                float dist = sqrtf(fmaxf(d2, EPS_F));
                if (diag) {
                    const int col = colbase + nf * 16 + cl;
                    if (row == col) dist = 1e-5f;   // exact diagonal sqrt(EPS)
                }
                const float dm = (yi == yj_[nf]) ? dist : 0.f;
                cs_all[nf] += dist;
                cs_same[nf] += dm;
                rs_all[mf * 4 + r] += dist;
                rs_same[mf * 4 + r] += dm;
            }
        }
    }

    // ---- col direction: value-split reduce 4 values over 4 g-lanes (3 shfl/kind)
    {
        const bool hi1 = (g >> 1) & 1;
#pragma unroll
        for (int j = 0; j < 2; ++j) {
            float sa_ = hi1 ? cs_all[j] : cs_all[j + 2];
            float ka_ = hi1 ? cs_all[j + 2] : cs_all[j];
            cs_all[j] = ka_ + __shfl_xor(sa_, 32);
            float ss_ = hi1 ? cs_same[j] : cs_same[j + 2];
            float ks_ = hi1 ? cs_same[j + 2] : cs_same[j];
            cs_same[j] = ks_ + __shfl_xor(ss_, 32);
        }
        const bool hi0 = g & 1;
        {
            float sa_ = hi0 ? cs_all[0] : cs_all[1];
            float ka_ = hi0 ? cs_all[1] : cs_all[0];
            cs_all[0] = ka_ + __shfl_xor(sa_, 16);
            float ss_ = hi0 ? cs_same[0] : cs_same[1];
            float ks_ = hi0 ? cs_same[1] : cs_same[0];
            cs_same[0] = ks_ + __shfl_xor(ss_, 16);
        }
        // lane (g,cl) now holds full col-sum for col = colbase + g*16 + cl
        const int ccol = colbase + g * 16 + cl;
        atomicAdd(&sum_all[ccol],  cs_all[0]);
        atomicAdd(&sum_same[ccol], cs_same[0]);
    }

    // ---- row direction (off-diag only): value-split reduce 16 over 16 cl-lanes
    if (!diag) {
#define RSTEP(h, mask, bit)                                                     \
        {                                                                       \
            const bool hi = (cl >> (bit)) & 1;                                  \
            _Pragma("unroll")                                                   \
            for (int j = 0; j < (h); ++j) {                                     \
                float sa_ = hi ? rs_all[j] : rs_all[j + (h)];                   \
                float ka_ = hi ? rs_all[j + (h)] : rs_all[j];                   \
                rs_all[j] = ka_ + __shfl_xor(sa_, (mask));                      \
                float ss_ = hi ? rs_same[j] : rs_same[j + (h)];                 \
                float ks_ = hi ? rs_same[j + (h)] : rs_same[j];                 \
                rs_same[j] = ks_ + __shfl_xor(ss_, (mask));                     \
            }                                                                   \
        }
        RSTEP(8, 8, 3)
        RSTEP(4, 4, 2)
        RSTEP(2, 2, 1)
        RSTEP(1, 1, 0)
#undef RSTEP
        // lane (g,cl) holds full row-sum for e=cl: row = rowbase+(cl>>2)*16+g*4+(cl&3)
        const int rrow = rowbase + (cl >> 2) * 16 + g * 4 + (cl & 3);
        atomicAdd(&sum_all[rrow],  rs_all[0]);
        atomicAdd(&sum_same[rrow], rs_same[0]);
    }
}

// ---------------------------------------------------------------------------
// Finalize: per-row loss terms -> atomicAdd partial means into out[0].
// ---------------------------------------------------------------------------
__global__ void finalize_kernel(const float* __restrict__ sum_same,
                                const float* __restrict__ sum_all,
                                const int* __restrict__ lbl,
                                const int* __restrict__ hist,
                                float* __restrict__ out) {
    __shared__ int lh[64];
    __shared__ float wsums[4];
    const int tid  = threadIdx.x;
    const int base = blockIdx.x * 512;
    if (tid < 64) lh[tid] = hist[tid];
    __syncthreads();

    float local = 0.f;
    for (int i = tid; i < 512; i += 256) {
        const int row  = base + i;
        const float cnt = (float)lh[lbl[row]];
        const float ss  = sum_same[row];
        const float sa  = sum_all[row];
        const float ap  = ss / cnt;
        const float an  = (sa - ss) / ((float)N - cnt);
        local += fmaxf(ap - an + MARGIN, 0.f);
    }
#pragma unroll
    for (int off = 32; off > 0; off >>= 1) local += __shfl_down(local, off);
    const int lane = tid & 63, wave = tid >> 6;
    if (lane == 0) wsums[wave] = local;
    __syncthreads();
    if (tid == 0)
        atomicAdd(out, (wsums[0] + wsums[1] + wsums[2] + wsums[3]) / (float)N);
}

// ---------------------------------------------------------------------------
extern "C" void kernel_launch(void* const* d_in, const int* in_sizes, int n_in,
                              void* d_out, int out_size, void* d_ws, size_t ws_size,
                              hipStream_t stream) {
    const float* xs     = (const float*)d_in[0];
    const int*   ys_raw = (const int*)d_in[1];

    float* ws        = (float*)d_ws;
    float* sum_same  = ws;                            // [N]
    float* sum_all   = ws + N;                        // [N]
    int*   hist      = (int*)(ws + 2 * N);            // [64]
    float* sqv       = ws + 2 * N + 64;               // [N]
    int*   lbl       = (int*)(ws + 3 * N + 64);       // [N]
    _Float16* x16    = (_Float16*)(ws + 4 * N + 64);  // [N*D] fp16 (4 MB), 16B-aligned

    // zero: sum_same, sum_all, hist, and the scalar output
    hipMemsetAsync(d_ws, 0, (size_t)(2 * N) * sizeof(float) + 64 * sizeof(int), stream);
    hipMemsetAsync(d_out, 0, sizeof(float), stream);

    label_prep_kernel<<<16, 256, 0, stream>>>(ys_raw, lbl, hist);
    prep_kernel<<<N / 4, 256, 0, stream>>>(xs, x16, sqv);

    pair_kernel<<<NBLK, 256, 0, stream>>>(x16, lbl, sqv, sum_same, sum_all);

    finalize_kernel<<<16, 256, 0, stream>>>(sum_same, sum_all, lbl, hist, (float*)d_out);
}

// Round 5
// 63.116 us; speedup vs baseline: 6.9677x; 1.2963x over previous
//
#include <hip/hip_runtime.h>
#include <math.h>

#define N 8192
#define D 256
#define TILE 128
#define NB (N / TILE)              // 64 panels
#define NBLK (NB * (NB + 1) / 2)   // 2080 upper-triangular blocks

typedef _Float16 half8 __attribute__((ext_vector_type(8)));
typedef float f32x4 __attribute__((ext_vector_type(4)));

constexpr float MARGIN = 0.5f;
constexpr float EPS_F  = 1e-10f;

// Blocked fragment-native layout for x16t (halves):
//   offset(row, k) = (row>>4)*4096 + (k>>3)*128 + (row&15)*8 + (k&7)
// A fragment load (16 rows x 8 halves x 4 k-groups) = 1024 contiguous bytes.

// ---------------------------------------------------------------------------
// Label prep: detect int64 vs int32 layout, normalize to int32, histogram.
// ---------------------------------------------------------------------------
__global__ void label_prep_kernel(const int* __restrict__ ys_raw,
                                  int* __restrict__ lbl, int* __restrict__ hist) {
    __shared__ int lh[64];
    __shared__ int bad_s;
    const int tid  = threadIdx.x;
    const int base = blockIdx.x * 512;
    if (tid < 64) lh[tid] = 0;
    if (tid == 0) bad_s = 0;
    __syncthreads();
    int bad = 0;
    for (int i = tid; i < 512; i += 256) bad |= (ys_raw[2 * (base + i) + 1] != 0);
    if (bad) atomicOr(&bad_s, 1);
    __syncthreads();
    const bool is64 = (bad_s == 0);
    for (int i = tid; i < 512; i += 256) {
        const int v = is64 ? ys_raw[2 * (base + i)] : ys_raw[base + i];
        lbl[base + i] = v;
        atomicAdd(&lh[v & 63], 1);
    }
    __syncthreads();
    if (tid < 64) atomicAdd(&hist[tid], lh[tid]);
}

// ---------------------------------------------------------------------------
// Fused prep: fp32 -> fp16 blocked layout + exact fp32 row squared norms.
// Grid: 512 blocks (one per 16-row tile), 256 threads.
// Thread (r = tid>>4, c16 = tid&15) handles row rb*16+r, k = c16*16..+15.
// ---------------------------------------------------------------------------
__global__ void prep_kernel(const float* __restrict__ xs,
                            _Float16* __restrict__ x16t, float* __restrict__ sq) {
    const int tid = threadIdx.x;
    const int r   = tid >> 4;
    const int c16 = tid & 15;
    const int rb  = blockIdx.x;
    const int row = rb * 16 + r;

    const float4* src = (const float4*)xs + (size_t)row * (D / 4) + c16 * 4;
    const float4 v0 = src[0], v1 = src[1], v2 = src[2], v3 = src[3];

    half8 h0 = { (_Float16)v0.x, (_Float16)v0.y, (_Float16)v0.z, (_Float16)v0.w,
                 (_Float16)v1.x, (_Float16)v1.y, (_Float16)v1.z, (_Float16)v1.w };
    half8 h1 = { (_Float16)v2.x, (_Float16)v2.y, (_Float16)v2.z, (_Float16)v2.w,
                 (_Float16)v3.x, (_Float16)v3.y, (_Float16)v3.z, (_Float16)v3.w };

    _Float16* dst = x16t + (size_t)rb * 4096 + (c16 * 2) * 128 + r * 8;
    *(half8*)dst         = h0;
    *(half8*)(dst + 128) = h1;

    float s = v0.x*v0.x + v0.y*v0.y + v0.z*v0.z + v0.w*v0.w
            + v1.x*v1.x + v1.y*v1.y + v1.z*v1.z + v1.w*v1.w
            + v2.x*v2.x + v2.y*v2.y + v2.z*v2.z + v2.w*v2.w
            + v3.x*v3.x + v3.y*v3.y + v3.z*v3.z + v3.w*v3.w;
#pragma unroll
    for (int off = 1; off < 16; off <<= 1) s += __shfl_xor(s, off);
    if (c16 == 0) sq[row] = s;
}

// ---------------------------------------------------------------------------
// Symmetric MFMA pair kernel, LDS-free: fragments loaded directly from the
// blocked global layout (1 KB coalesced loads, L1/L2-resident), explicit
// 2-stage software pipeline, no barriers. 2080 upper-tri blocks, 4 waves
// (2x2 of 64x64). Row/col sums via value-split butterflies, 4 atomics/lane.
// ---------------------------------------------------------------------------
__global__ __launch_bounds__(256) void pair_kernel(
    const _Float16* __restrict__ x16t, const int* __restrict__ lbl,
    const float* __restrict__ sq,
    float* __restrict__ sum_same, float* __restrict__ sum_all) {

    // ---- XCD-bijective swizzle (2080 % 8 == 0 -> exact chunking) ----
    const int t = (blockIdx.x % 8) * (NBLK / 8) + blockIdx.x / 8;

    // ---- decode upper-triangular block index: t -> (bi, bj), bi<=bj ----
    int bj = (int)((sqrtf(8.f * (float)t + 1.f) - 1.f) * 0.5f);
    while ((bj + 1) * (bj + 2) / 2 <= t) ++bj;
    while (bj * (bj + 1) / 2 > t) --bj;
    const int bi    = t - bj * (bj + 1) / 2;
    const bool diag = (bi == bj);
    const int i0 = bi * TILE;
    const int j0 = bj * TILE;

    const int tid  = threadIdx.x;
    const int w    = tid >> 6;
    const int lane = tid & 63;
    const int wm   = w >> 1;
    const int wn   = w & 1;
    const int cl   = lane & 15;
    const int g    = lane >> 4;

    f32x4 acc[4][4];
#pragma unroll
    for (int a = 0; a < 4; ++a)
#pragma unroll
        for (int b = 0; b < 4; ++b) acc[a][b] = (f32x4){0.f, 0.f, 0.f, 0.f};

    // per-lane fragment base: row-tile (i0>>4 + wm*4 + mf), k-chunk g, row cl
    const _Float16* pa = x16t + (size_t)((i0 >> 4) + wm * 4) * 4096 + g * 128 + cl * 8;
    const _Float16* pb = x16t + (size_t)((j0 >> 4) + wn * 4) * 4096 + g * 128 + cl * 8;

    half8 af[2][4], bf[2][4];
#pragma unroll
    for (int mf = 0; mf < 4; ++mf) {
        af[0][mf] = *(const half8*)(pa + mf * 4096);
        bf[0][mf] = *(const half8*)(pb + mf * 4096);
    }

#pragma unroll
    for (int t8 = 0; t8 < 8; ++t8) {           // fully unrolled -> static [t8&1]
        if (t8 < 7) {
            const int koff = (t8 + 1) * 512;   // 32 k per iter = 512 halves
#pragma unroll
            for (int mf = 0; mf < 4; ++mf) {
                af[(t8 + 1) & 1][mf] = *(const half8*)(pa + mf * 4096 + koff);
                bf[(t8 + 1) & 1][mf] = *(const half8*)(pb + mf * 4096 + koff);
            }
        }
#pragma unroll
        for (int mf = 0; mf < 4; ++mf)
#pragma unroll
            for (int nf = 0; nf < 4; ++nf)
                acc[mf][nf] = __builtin_amdgcn_mfma_f32_16x16x32_f16(
                    af[t8 & 1][mf], bf[t8 & 1][nf], acc[mf][nf], 0, 0, 0);
    }

    // ---- epilogue ----
    // C layout (m89): col = lane&15 (j-local), row = (lane>>4)*4 + reg (i-local)
    const int rowbase = i0 + wm * 64;
    const int colbase = j0 + wn * 64;

    float sqj_[4];
    int   yj_[4];
#pragma unroll
    for (int nf = 0; nf < 4; ++nf) {
        const int c = colbase + nf * 16 + cl;
        sqj_[nf] = sq[c];
        yj_[nf]  = lbl[c];
    }

    float cs_all[4], cs_same[4];      // col sums (over i) -> rows of panel bj
#pragma unroll
    for (int nf = 0; nf < 4; ++nf) { cs_all[nf] = 0.f; cs_same[nf] = 0.f; }
    float rs_all[16], rs_same[16];    // row sums (over j) -> rows of panel bi
#pragma unroll
    for (int e = 0; e < 16; ++e) { rs_all[e] = 0.f; rs_same[e] = 0.f; }

#pragma unroll
    for (int mf = 0; mf < 4; ++mf) {
#pragma unroll
        for (int r = 0; r < 4; ++r) {
            const int row   = rowbase + mf * 16 + g * 4 + r;
            const float sqi = sq[row];
            const int   yi  = lbl[row];
#pragma unroll
            for (int nf = 0; nf < 4; ++nf) {
                float d2   = sqi + sqj_[nf] - 2.f * acc[mf][nf][r];
                float dist = __builtin_amdgcn_sqrtf(fmaxf(d2, EPS_F));
                if (diag) {
                    const int col = colbase + nf * 16 + cl;
                    if (row == col) dist = 1e-5f;   // exact diagonal sqrt(EPS)
                }
                const float dm = (yi == yj_[nf]) ? dist : 0.f;
                cs_all[nf] += dist;
                cs_same[nf] += dm;
                rs_all[mf * 4 + r] += dist;
                rs_same[mf * 4 + r] += dm;
            }
        }
    }

    // ---- col direction: value-split reduce 4 values over 4 g-lanes
    {
        const bool hi1 = (g >> 1) & 1;
#pragma unroll
        for (int j = 0; j < 2; ++j) {
            float sa_ = hi1 ? cs_all[j] : cs_all[j + 2];
            float ka_ = hi1 ? cs_all[j + 2] : cs_all[j];
            cs_all[j] = ka_ + __shfl_xor(sa_, 32);
            float ss_ = hi1 ? cs_same[j] : cs_same[j + 2];
            float ks_ = hi1 ? cs_same[j + 2] : cs_same[j];
            cs_same[j] = ks_ + __shfl_xor(ss_, 32);
        }
        const bool hi0 = g & 1;
        {
            float sa_ = hi0 ? cs_all[0] : cs_all[1];
            float ka_ = hi0 ? cs_all[1] : cs_all[0];
            cs_all[0] = ka_ + __shfl_xor(sa_, 16);
            float ss_ = hi0 ? cs_same[0] : cs_same[1];
            float ks_ = hi0 ? cs_same[1] : cs_same[0];
            cs_same[0] = ks_ + __shfl_xor(ss_, 16);
        }
        const int ccol = colbase + g * 16 + cl;
        atomicAdd(&sum_all[ccol],  cs_all[0]);
        atomicAdd(&sum_same[ccol], cs_same[0]);
    }

    // ---- row direction (off-diag only): value-split reduce 16 over 16 lanes
    if (!diag) {
#define RSTEP(h, mask, bit)                                                     \
        {                                                                       \
            const bool hi = (cl >> (bit)) & 1;                                  \
            _Pragma("unroll")                                                   \
            for (int j = 0; j < (h); ++j) {                                     \
                float sa_ = hi ? rs_all[j] : rs_all[j + (h)];                   \
                float ka_ = hi ? rs_all[j + (h)] : rs_all[j];                   \
                rs_all[j] = ka_ + __shfl_xor(sa_, (mask));                      \
                float ss_ = hi ? rs_same[j] : rs_same[j + (h)];                 \
                float ks_ = hi ? rs_same[j + (h)] : rs_same[j];                 \
                rs_same[j] = ks_ + __shfl_xor(ss_, (mask));                     \
            }                                                                   \
        }
        RSTEP(8, 8, 3)
        RSTEP(4, 4, 2)
        RSTEP(2, 2, 1)
        RSTEP(1, 1, 0)
#undef RSTEP
        const int rrow = rowbase + (cl >> 2) * 16 + g * 4 + (cl & 3);
        atomicAdd(&sum_all[rrow],  rs_all[0]);
        atomicAdd(&sum_same[rrow], rs_same[0]);
    }
}

// ---------------------------------------------------------------------------
// Finalize: per-row loss terms -> atomicAdd partial means into out[0].
// ---------------------------------------------------------------------------
__global__ void finalize_kernel(const float* __restrict__ sum_same,
                                const float* __restrict__ sum_all,
                                const int* __restrict__ lbl,
                                const int* __restrict__ hist,
                                float* __restrict__ out) {
    __shared__ int lh[64];
    __shared__ float wsums[4];
    const int tid  = threadIdx.x;
    const int base = blockIdx.x * 512;
    if (tid < 64) lh[tid] = hist[tid];
    __syncthreads();

    float local = 0.f;
    for (int i = tid; i < 512; i += 256) {
        const int row  = base + i;
        const float cnt = (float)lh[lbl[row]];
        const float ss  = sum_same[row];
        const float sa  = sum_all[row];
        const float ap  = ss / cnt;
        const float an  = (sa - ss) / ((float)N - cnt);
        local += fmaxf(ap - an + MARGIN, 0.f);
    }
#pragma unroll
    for (int off = 32; off > 0; off >>= 1) local += __shfl_down(local, off);
    const int lane = tid & 63, wave = tid >> 6;
    if (lane == 0) wsums[wave] = local;
    __syncthreads();
    if (tid == 0)
        atomicAdd(out, (wsums[0] + wsums[1] + wsums[2] + wsums[3]) / (float)N);
}

// ---------------------------------------------------------------------------
extern "C" void kernel_launch(void* const* d_in, const int* in_sizes, int n_in,
                              void* d_out, int out_size, void* d_ws, size_t ws_size,
                              hipStream_t stream) {
    const float* xs     = (const float*)d_in[0];
    const int*   ys_raw = (const int*)d_in[1];

    float* ws        = (float*)d_ws;
    float* sum_same  = ws;                            // [N]
    float* sum_all   = ws + N;                        // [N]
    int*   hist      = (int*)(ws + 2 * N);            // [64]
    float* sqv       = ws + 2 * N + 64;               // [N]
    int*   lbl       = (int*)(ws + 3 * N + 64);       // [N]
    _Float16* x16t   = (_Float16*)(ws + 4 * N + 64);  // [N*D] blocked fp16 (4 MB)

    hipMemsetAsync(d_ws, 0, (size_t)(2 * N) * sizeof(float) + 64 * sizeof(int), stream);
    hipMemsetAsync(d_out, 0, sizeof(float), stream);

    label_prep_kernel<<<16, 256, 0, stream>>>(ys_raw, lbl, hist);
    prep_kernel<<<N / 16, 256, 0, stream>>>(xs, x16t, sqv);

    pair_kernel<<<NBLK, 256, 0, stream>>>(x16t, lbl, sqv, sum_same, sum_all);

    finalize_kernel<<<16, 256, 0, stream>>>(sum_same, sum_all, lbl, hist, (float*)d_out);
}

// Round 7
// 61.527 us; speedup vs baseline: 7.1476x; 1.0258x over previous
//
#include <hip/hip_runtime.h>
#include <math.h>

#define N 8192
#define D 256
#define TILE 128
#define NB (N / TILE)              // 64 panels
#define NBLK (NB * (NB + 1) / 2)   // 2080 upper-triangular blocks

typedef _Float16 half8 __attribute__((ext_vector_type(8)));
typedef float f32x4 __attribute__((ext_vector_type(4)));

constexpr float MARGIN = 0.5f;
constexpr float EPS_F  = 1e-10f;

// Blocked fragment-native layout for x16t (halves):
//   offset(row, k) = (row>>4)*4096 + (k>>3)*128 + (row&15)*8 + (k&7)
// A fragment load (16 rows x 8 halves x 4 k-groups) = 1024 contiguous bytes.

// ---------------------------------------------------------------------------
// Fused prologue (one dispatch, 512 blocks x 256 thr):
//   all blocks  : fp32 -> fp16 blocked layout + exact fp32 row sq-norms
//   blocks 0-15 : label int64/int32 detect + normalize to int32
//   blocks 16-47: zero sum_same/sum_all (512 floats each)
//   block 48    : zero out[0]
// ---------------------------------------------------------------------------
__global__ void prep_kernel(const float* __restrict__ xs,
                            const int* __restrict__ ys_raw,
                            _Float16* __restrict__ x16t, float* __restrict__ sq,
                            int* __restrict__ lbl, float* __restrict__ sums,
                            float* __restrict__ out) {
    const int tid = threadIdx.x;
    const int rb  = blockIdx.x;

    // ---- convert + sq (every block handles a 16-row tile) ----
    {
        const int r   = tid >> 4;
        const int c16 = tid & 15;
        const int row = rb * 16 + r;

        const float4* src = (const float4*)xs + (size_t)row * (D / 4) + c16 * 4;
        const float4 v0 = src[0], v1 = src[1], v2 = src[2], v3 = src[3];

        half8 h0 = { (_Float16)v0.x, (_Float16)v0.y, (_Float16)v0.z, (_Float16)v0.w,
                     (_Float16)v1.x, (_Float16)v1.y, (_Float16)v1.z, (_Float16)v1.w };
        half8 h1 = { (_Float16)v2.x, (_Float16)v2.y, (_Float16)v2.z, (_Float16)v2.w,
                     (_Float16)v3.x, (_Float16)v3.y, (_Float16)v3.z, (_Float16)v3.w };

        _Float16* dst = x16t + (size_t)rb * 4096 + (c16 * 2) * 128 + r * 8;
        *(half8*)dst         = h0;
        *(half8*)(dst + 128) = h1;

        float s = v0.x*v0.x + v0.y*v0.y + v0.z*v0.z + v0.w*v0.w
                + v1.x*v1.x + v1.y*v1.y + v1.z*v1.z + v1.w*v1.w
                + v2.x*v2.x + v2.y*v2.y + v2.z*v2.z + v2.w*v2.w
                + v3.x*v3.x + v3.y*v3.y + v3.z*v3.z + v3.w*v3.w;
#pragma unroll
        for (int off = 1; off < 16; off <<= 1) s += __shfl_xor(s, off);
        if (c16 == 0) sq[row] = s;
    }

    // ---- labels (blocks 0-15, 512 labels each) ----
    if (rb < 16) {
        __shared__ int bad_s;
        const int base = rb * 512;
        if (tid == 0) bad_s = 0;
        __syncthreads();
        int bad = 0;
        for (int i = tid; i < 512; i += 256) bad |= (ys_raw[2 * (base + i) + 1] != 0);
        if (bad) atomicOr(&bad_s, 1);
        __syncthreads();
        const bool is64 = (bad_s == 0);
        for (int i = tid; i < 512; i += 256)
            lbl[base + i] = is64 ? ys_raw[2 * (base + i)] : ys_raw[base + i];
    }

    // ---- zero accumulators (blocks 16-47: 32 blocks x 512 floats = 2N) ----
    if (rb >= 16 && rb < 48) {
        const int off = (rb - 16) * 512 + tid;
        sums[off]       = 0.f;
        sums[off + 256] = 0.f;
    }
    if (rb == 48 && tid == 0) out[0] = 0.f;
}

// ---------------------------------------------------------------------------
// Symmetric MFMA pair kernel, LDS-free: fragments loaded directly from the
// blocked global layout (1 KB coalesced loads, L1/L2-resident), explicit
// 2-stage software pipeline, no barriers. 2080 upper-tri blocks, 4 waves
// (2x2 of 64x64). launch_bounds(256,3) -> 3 waves/SIMD for latency hiding.
// ---------------------------------------------------------------------------
__global__ __launch_bounds__(256, 3) void pair_kernel(
    const _Float16* __restrict__ x16t, const int* __restrict__ lbl,
    const float* __restrict__ sq,
    float* __restrict__ sum_same, float* __restrict__ sum_all) {

    // ---- XCD-bijective swizzle (2080 % 8 == 0 -> exact chunking) ----
    const int t = (blockIdx.x % 8) * (NBLK / 8) + blockIdx.x / 8;

    // ---- decode upper-triangular block index: t -> (bi, bj), bi<=bj ----
    int bj = (int)((sqrtf(8.f * (float)t + 1.f) - 1.f) * 0.5f);
    while ((bj + 1) * (bj + 2) / 2 <= t) ++bj;
    while (bj * (bj + 1) / 2 > t) --bj;
    const int bi    = t - bj * (bj + 1) / 2;
    const bool diag = (bi == bj);
    const int i0 = bi * TILE;
    const int j0 = bj * TILE;

    const int tid  = threadIdx.x;
    const int w    = tid >> 6;
    const int lane = tid & 63;
    const int wm   = w >> 1;
    const int wn   = w & 1;
    const int cl   = lane & 15;
    const int g    = lane >> 4;

    f32x4 acc[4][4];
#pragma unroll
    for (int a = 0; a < 4; ++a)
#pragma unroll
        for (int b = 0; b < 4; ++b) acc[a][b] = (f32x4){0.f, 0.f, 0.f, 0.f};

    // per-lane fragment base: row-tile (i0>>4 + wm*4 + mf), k-chunk g, row cl
    const _Float16* pa = x16t + (size_t)((i0 >> 4) + wm * 4) * 4096 + g * 128 + cl * 8;
    const _Float16* pb = x16t + (size_t)((j0 >> 4) + wn * 4) * 4096 + g * 128 + cl * 8;

    half8 af[2][4], bf[2][4];
#pragma unroll
    for (int mf = 0; mf < 4; ++mf) {
        af[0][mf] = *(const half8*)(pa + mf * 4096);
        bf[0][mf] = *(const half8*)(pb + mf * 4096);
    }

#pragma unroll
    for (int t8 = 0; t8 < 8; ++t8) {           // fully unrolled -> static [t8&1]
        if (t8 < 7) {
            const int koff = (t8 + 1) * 512;   // 32 k per iter = 512 halves
#pragma unroll
            for (int mf = 0; mf < 4; ++mf) {
                af[(t8 + 1) & 1][mf] = *(const half8*)(pa + mf * 4096 + koff);
                bf[(t8 + 1) & 1][mf] = *(const half8*)(pb + mf * 4096 + koff);
            }
        }
#pragma unroll
        for (int mf = 0; mf < 4; ++mf)
#pragma unroll
            for (int nf = 0; nf < 4; ++nf)
                acc[mf][nf] = __builtin_amdgcn_mfma_f32_16x16x32_f16(
                    af[t8 & 1][mf], bf[t8 & 1][nf], acc[mf][nf], 0, 0, 0);
    }

    // ---- epilogue ----
    // C layout (m89): col = lane&15 (j-local), row = (lane>>4)*4 + reg (i-local)
    const int rowbase = i0 + wm * 64;
    const int colbase = j0 + wn * 64;

    float sqj_[4];
    int   yj_[4];
#pragma unroll
    for (int nf = 0; nf < 4; ++nf) {
        const int c = colbase + nf * 16 + cl;
        sqj_[nf] = sq[c];
        yj_[nf]  = lbl[c];
    }

    float cs_all[4], cs_same[4];      // col sums (over i) -> rows of panel bj
#pragma unroll
    for (int nf = 0; nf < 4; ++nf) { cs_all[nf] = 0.f; cs_same[nf] = 0.f; }

    // two batches of 8 rows each (mf in {2b, 2b+1}) to halve register peak
#pragma unroll
    for (int b = 0; b < 2; ++b) {
        float rs_all[8], rs_same[8];
#pragma unroll
        for (int e = 0; e < 8; ++e) { rs_all[e] = 0.f; rs_same[e] = 0.f; }

#pragma unroll
        for (int mh = 0; mh < 2; ++mh) {
            const int mf = 2 * b + mh;
#pragma unroll
            for (int r = 0; r < 4; ++r) {
                const int row   = rowbase + mf * 16 + g * 4 + r;
                const float sqi = sq[row];
                const int   yi  = lbl[row];
#pragma unroll
                for (int nf = 0; nf < 4; ++nf) {
                    float d2   = sqi + sqj_[nf] - 2.f * acc[mf][nf][r];
                    float dist = __builtin_amdgcn_sqrtf(fmaxf(d2, EPS_F));
                    if (diag) {
                        const int col = colbase + nf * 16 + cl;
                        if (row == col) dist = 1e-5f;   // exact diagonal sqrt(EPS)
                    }
                    const float dm = (yi == yj_[nf]) ? dist : 0.f;
                    cs_all[nf] += dist;
                    cs_same[nf] += dm;
                    rs_all[mh * 4 + r] += dist;
                    rs_same[mh * 4 + r] += dm;
                }
            }
        }

        // row direction (off-diag only): value-split 8 values over 16 lanes.
        // Steps (mask 8,4,2) collapse 8 values -> 1 per lane; the closing
        // mask-1 step (plain add, no split) completes the sum over all 16
        // lanes. Lanes cl and cl^1 then hold duplicates of entry e = cl>>1;
        // even-cl lanes write. [Round-6 bug: this last step was missing.]
        if (!diag) {
#define RSTEP(h, mask, bit)                                                     \
            {                                                                   \
                const bool hi = (cl >> (bit)) & 1;                              \
                _Pragma("unroll")                                               \
                for (int j = 0; j < (h); ++j) {                                 \
                    float sa_ = hi ? rs_all[j] : rs_all[j + (h)];               \
                    float ka_ = hi ? rs_all[j + (h)] : rs_all[j];               \
                    rs_all[j] = ka_ + __shfl_xor(sa_, (mask));                  \
                    float ss_ = hi ? rs_same[j] : rs_same[j + (h)];             \
                    float ks_ = hi ? rs_same[j + (h)] : rs_same[j];             \
                    rs_same[j] = ks_ + __shfl_xor(ss_, (mask));                 \
                }                                                               \
            }
            RSTEP(4, 8, 3)
            RSTEP(2, 4, 2)
            RSTEP(1, 2, 1)
#undef RSTEP
            rs_all[0]  += __shfl_xor(rs_all[0], 1);   // closing stage (mask 1)
            rs_same[0] += __shfl_xor(rs_same[0], 1);

            const int e    = cl >> 1;
            const int rrow = rowbase + (2 * b + (e >> 2)) * 16 + g * 4 + (e & 3);
            if (!(cl & 1)) {
                atomicAdd(&sum_all[rrow],  rs_all[0]);
                atomicAdd(&sum_same[rrow], rs_same[0]);
            }
        }
    }

    // ---- col direction: value-split reduce 4 values over 4 g-lanes
    {
        const bool hi1 = (g >> 1) & 1;
#pragma unroll
        for (int j = 0; j < 2; ++j) {
            float sa_ = hi1 ? cs_all[j] : cs_all[j + 2];
            float ka_ = hi1 ? cs_all[j + 2] : cs_all[j];
            cs_all[j] = ka_ + __shfl_xor(sa_, 32);
            float ss_ = hi1 ? cs_same[j] : cs_same[j + 2];
            float ks_ = hi1 ? cs_same[j + 2] : cs_same[j];
            cs_same[j] = ks_ + __shfl_xor(ss_, 32);
        }
        const bool hi0 = g & 1;
        {
            float sa_ = hi0 ? cs_all[0] : cs_all[1];
            float ka_ = hi0 ? cs_all[1] : cs_all[0];
            cs_all[0] = ka_ + __shfl_xor(sa_, 16);
            float ss_ = hi0 ? cs_same[0] : cs_same[1];
            float ks_ = hi0 ? cs_same[1] : cs_same[0];
            cs_same[0] = ks_ + __shfl_xor(ss_, 16);
        }
        const int ccol = colbase + g * 16 + cl;
        atomicAdd(&sum_all[ccol],  cs_all[0]);
        atomicAdd(&sum_same[ccol], cs_same[0]);
    }
}

// ---------------------------------------------------------------------------
// Finalize: per-block LDS label histogram -> per-row loss -> atomicAdd out.
// ---------------------------------------------------------------------------
__global__ void finalize_kernel(const float* __restrict__ sum_same,
                                const float* __restrict__ sum_all,
                                const int* __restrict__ lbl,
                                float* __restrict__ out) {
    __shared__ int lh[64];
    __shared__ float wsums[4];
    const int tid  = threadIdx.x;
    const int base = blockIdx.x * 512;
    if (tid < 64) lh[tid] = 0;
    __syncthreads();
    for (int i = tid; i < N; i += 256) atomicAdd(&lh[lbl[i]], 1);
    __syncthreads();

    float local = 0.f;
    for (int i = tid; i < 512; i += 256) {
        const int row  = base + i;
        const float cnt = (float)lh[lbl[row]];
        const float ss  = sum_same[row];
        const float sa  = sum_all[row];
        const float ap  = ss / cnt;
        const float an  = (sa - ss) / ((float)N - cnt);
        local += fmaxf(ap - an + MARGIN, 0.f);
    }
#pragma unroll
    for (int off = 32; off > 0; off >>= 1) local += __shfl_down(local, off);
    const int lane = tid & 63, wave = tid >> 6;
    if (lane == 0) wsums[wave] = local;
    __syncthreads();
    if (tid == 0)
        atomicAdd(out, (wsums[0] + wsums[1] + wsums[2] + wsums[3]) / (float)N);
}

// ---------------------------------------------------------------------------
extern "C" void kernel_launch(void* const* d_in, const int* in_sizes, int n_in,
                              void* d_out, int out_size, void* d_ws, size_t ws_size,
                              hipStream_t stream) {
    const float* xs     = (const float*)d_in[0];
    const int*   ys_raw = (const int*)d_in[1];

    float* ws        = (float*)d_ws;
    float* sum_same  = ws;                            // [N]
    float* sum_all   = ws + N;                        // [N]
    float* sqv       = ws + 2 * N;                    // [N]
    int*   lbl       = (int*)(ws + 3 * N);            // [N]
    _Float16* x16t   = (_Float16*)(ws + 4 * N);       // [N*D] blocked fp16 (4 MB)

    prep_kernel<<<N / 16, 256, 0, stream>>>(xs, ys_raw, x16t, sqv, lbl,
                                            sum_same, (float*)d_out);

    pair_kernel<<<NBLK, 256, 0, stream>>>(x16t, lbl, sqv, sum_same, sum_all);

    finalize_kernel<<<16, 256, 0, stream>>>(sum_same, sum_all, lbl, (float*)d_out);
}